// Round 2
// baseline (111.169 us; speedup 1.0000x reference)
//
#include <hip/hip_runtime.h>

// Problem constants (match reference):
//   VOCAB=100000, DIM=50, B=4096, L=512, OUT=20
// Inputs (setup_inputs order):
//   d_in[0] x         [B*L]      int
//   d_in[1] lengths   [B]        int
//   d_in[2] emb_table [VOCAB*50] float
//   d_in[3] W         [20*50]    float
//   d_in[4] b         [20]       float
// Output: logits [B*20] float

#define LMAX 512
#define DIMV 50
#define OUTV 20

__global__ __launch_bounds__(256) void fused_embed_mean_linear(
    const int*   __restrict__ x,
    const int*   __restrict__ lengths,
    const float* __restrict__ emb,
    const float* __restrict__ W,
    const float* __restrict__ bias,
    float*       __restrict__ out)
{
    const int b    = blockIdx.x;
    const int tid  = threadIdx.x;
    const int wave = tid >> 6;
    const int lane = tid & 63;

    __shared__ int   sidx[LMAX];
    __shared__ float sacc[4][DIMV];
    __shared__ float srep[DIMV];

    const int len = lengths[b];

    // Stage this sample's token indices into LDS (coalesced).
    const int xbase = b * LMAX;
    for (int i = tid; i < len; i += 256) sidx[i] = x[xbase + i];
    __syncthreads();

    // Gather-accumulate: lane d (<50) sums emb[idx][d] over tokens.
    // Waves stride tokens by 4; 8 independent gathers in flight per wave
    // (latency-bound on L2 ~200cy — MLP is the lever). Two accumulators
    // shorten the dependent add chain.
    if (lane < DIMV) {
        float acc0 = 0.f, acc1 = 0.f;
        int l = wave;
        for (; l + 28 < len; l += 32) {
            float v0 = emb[sidx[l      ] * DIMV + lane];
            float v1 = emb[sidx[l + 4  ] * DIMV + lane];
            float v2 = emb[sidx[l + 8  ] * DIMV + lane];
            float v3 = emb[sidx[l + 12 ] * DIMV + lane];
            float v4 = emb[sidx[l + 16 ] * DIMV + lane];
            float v5 = emb[sidx[l + 20 ] * DIMV + lane];
            float v6 = emb[sidx[l + 24 ] * DIMV + lane];
            float v7 = emb[sidx[l + 28 ] * DIMV + lane];
            acc0 += (v0 + v1) + (v2 + v3);
            acc1 += (v4 + v5) + (v6 + v7);
        }
        for (; l < len; l += 4)
            acc0 += emb[sidx[l] * DIMV + lane];
        sacc[wave][lane] = acc0 + acc1;
    }
    __syncthreads();

    // Cross-wave reduce + mean + ReLU
    if (tid < DIMV) {
        float s = sacc[0][tid] + sacc[1][tid] + sacc[2][tid] + sacc[3][tid];
        s /= (float)len;
        srep[tid] = fmaxf(s, 0.f);
    }
    __syncthreads();

    // Tiny matvec: 20 outputs, each a 50-dot with W row + bias.
    if (tid < OUTV) {
        float s = bias[tid];
        const float* wr = W + tid * DIMV;
        #pragma unroll
        for (int d = 0; d < DIMV; ++d) s += srep[d] * wr[d];
        out[b * OUTV + tid] = s;
    }
}

extern "C" void kernel_launch(void* const* d_in, const int* in_sizes, int n_in,
                              void* d_out, int out_size, void* d_ws, size_t ws_size,
                              hipStream_t stream) {
    const int*   x       = (const int*)  d_in[0];
    const int*   lengths = (const int*)  d_in[1];
    const float* emb     = (const float*)d_in[2];
    const float* W       = (const float*)d_in[3];
    const float* bias    = (const float*)d_in[4];
    float* out = (float*)d_out;

    const int B = in_sizes[1];  // 4096
    fused_embed_mean_linear<<<B, 256, 0, stream>>>(x, lengths, emb, W, bias, out);
}